// Round 4
// baseline (416.469 us; speedup 1.0000x reference)
//
#include <hip/hip_runtime.h>
#include <stdint.h>

typedef _Float16 f16;
typedef _Float16 f16x8 __attribute__((ext_vector_type(8)));
typedef _Float16 f16x4 __attribute__((ext_vector_type(4)));
typedef float f32x4 __attribute__((ext_vector_type(4)));

#define B_ROWS 4096
#define C_COLS 32768
#define D_DIM 256
// log2(e) / 0.05
#define LOG2E_OVER_TEMP 28.853900817779268f

#define BM 256                  // rows per block (4 waves x 64 rows)
#define BC 32                   // cols per LDS tile (16 KB/tile, dbuf = 32 KB)
#define CSPLIT 64
#define CPB (C_COLS / CSPLIT)   // 512 cols per block
#define CTILES (CPB / BC)       // 16 tiles
#define NWAVES 4

typedef __attribute__((address_space(3))) char lds_char_t;
typedef __attribute__((address_space(1))) const char glb_char_t;

// ---- kernel 1: fused  (a) fp32->fp16 convert of centrals   [blocks 0..4095]
//                       (b) row-normalize x (pre-scaled) + exact label exp [blocks 4096..5119]
#define CVT_BLOCKS 4096
__global__ void prep_all(const float* __restrict__ x, const float* __restrict__ cent,
                         const int* __restrict__ labels, f16* __restrict__ f16c,
                         f16* __restrict__ f, float* __restrict__ elab) {
  int blk = blockIdx.x;
  if (blk < CVT_BLOCKS) {
    int i = blk * blockDim.x + threadIdx.x;           // 0 .. 1048575 chunk of 8
    const float4* p = (const float4*)(cent + (size_t)i * 8);
    float4 v0 = p[0], v1 = p[1];
    f16x8 o;
    o[0] = (f16)v0.x; o[1] = (f16)v0.y; o[2] = (f16)v0.z; o[3] = (f16)v0.w;
    o[4] = (f16)v1.x; o[5] = (f16)v1.y; o[6] = (f16)v1.z; o[7] = (f16)v1.w;
    *(f16x8*)(f16c + (size_t)i * 8) = o;
  } else {
    int row = (blk - CVT_BLOCKS) * (blockDim.x >> 6) + (threadIdx.x >> 6);
    int lane = threadIdx.x & 63;
    int lab = labels[row];
    const float4 xv = *(const float4*)(x + (size_t)row * D_DIM + lane * 4);
    const float4 cv = *(const float4*)(cent + (size_t)lab * D_DIM + lane * 4);
    float ss = xv.x * xv.x + xv.y * xv.y + xv.z * xv.z + xv.w * xv.w;
    float dc = xv.x * cv.x + xv.y * cv.y + xv.z * cv.z + xv.w * cv.w;
    #pragma unroll
    for (int m = 1; m < 64; m <<= 1) {
      ss += __shfl_xor(ss, m, 64);
      dc += __shfl_xor(dc, m, 64);
    }
    float inv = 1.0f / sqrtf(ss);
    float sc = inv * LOG2E_OVER_TEMP;   // A pre-scaled: GEMM acc is the exp2 arg
    f16x4 o;
    o[0] = (f16)(xv.x * sc); o[1] = (f16)(xv.y * sc);
    o[2] = (f16)(xv.z * sc); o[3] = (f16)(xv.w * sc);
    *(f16x4*)(f + (size_t)row * D_DIM + lane * 4) = o;
    if (lane == 0) elab[row] = exp2f(dc * inv * LOG2E_OVER_TEMP);
  }
}

// ---- staging: async global->LDS, 16B/lane, pre-swizzled global source ----
// LDS target layout: chunk (c, kc) at byte (c*512 + kc*16) ^ ((c&7)<<4).
// global_load_lds writes linearly, so the lane filling slot s fetches the
// chunk that belongs there: c = s>>5, kc = (s&31)^(c&7).  Tile = 32 x 256 f16.
__device__ __forceinline__ void stage_tile(const f16* __restrict__ src, char* buf,
                                           int w, int lane) {
  #pragma unroll
  for (int i = 0; i < 4; i++) {
    int slot_hi = i * NWAVES + w;          // wave-uniform, 0..15
    int s = slot_hi * 64 + lane;           // 0..1023
    int c = s >> 5;                        // 0..31
    int kc = (s & 31) ^ (c & 7);
    const f16* g = src + c * D_DIM + kc * 8;
    __builtin_amdgcn_global_load_lds((glb_char_t*)(const void*)g,
                                     (lds_char_t*)(void*)(buf + slot_hi * 1024),
                                     16, 0, 0);
  }
}

// ---- kernel 2: fused f16 GEMM + exp + row-sum ----
// 1024 blocks x 256 threads (4 waves), 4 blocks/CU (LDS 32KB, VGPR<=128).
// Each wave owns 64 rows in registers; B tile double-buffered, async-staged.
__global__ void __launch_bounds__(256, 4)
gemm_expsum(const f16* __restrict__ f, const f16* __restrict__ cent,
            float* __restrict__ partials) {
  __shared__ char Bs[2][BC * D_DIM * 2];   // 2 x 16 KB
  const int tid = threadIdx.x;
  const int w = tid >> 6, lane = tid & 63;
  const int fr = lane & 15, kq = lane >> 4;

  // XCD-aware decode: xcd = bid&7 owns cs in [xcd*8, xcd*8+8) -> B-slice L2-local
  const int bid = blockIdx.x;
  const int xcd = bid & 7;
  const int j = bid >> 3;                  // 0..127
  const int bx = j & 15;                   // row-block 0..15
  const int cs = xcd * 8 + (j >> 4);       // col-split 0..63
  const int brow0 = bx * BM;
  const int c0 = cs * CPB;

  // A fragments: rows brow0 + w*64 + rf*16 + fr, k = kk*32 + kq*8 .. +8
  f16x8 a[4][8];
  {
    const f16* base = f + (size_t)(brow0 + w * 64 + fr) * D_DIM + kq * 8;
    #pragma unroll
    for (int rf = 0; rf < 4; rf++)
      #pragma unroll
      for (int kk = 0; kk < 8; kk++)
        a[rf][kk] = *(const f16x8*)(base + rf * 16 * D_DIM + kk * 32);
  }

  float s[4][4] = {{0.f,0.f,0.f,0.f},{0.f,0.f,0.f,0.f},{0.f,0.f,0.f,0.f},{0.f,0.f,0.f,0.f}};
  const f32x4 vzero = {0.f, 0.f, 0.f, 0.f};

  stage_tile(cent + (size_t)c0 * D_DIM, Bs[0], w, lane);

  for (int t = 0; t < CTILES; t++) {
    __syncthreads();   // implicit vmcnt(0): stage(t) landed; readers of buf[(t+1)&1] done
    if (t + 1 < CTILES)
      stage_tile(cent + (size_t)(c0 + (t + 1) * BC) * D_DIM, Bs[(t + 1) & 1], w, lane);

    const char* buf = Bs[t & 1];
    #pragma unroll
    for (int cf = 0; cf < 2; cf++) {
      f32x4 acc[4] = {vzero, vzero, vzero, vzero};
      #pragma unroll
      for (int kk = 0; kk < 8; kk++) {
        const int c = cf * 16 + fr;
        const int off = (c * 512 + kk * 64 + kq * 16) ^ ((c & 7) << 4);
        f16x8 bf = *(const f16x8*)(buf + off);
        #pragma unroll
        for (int rf = 0; rf < 4; rf++)
          acc[rf] = __builtin_amdgcn_mfma_f32_16x16x32_f16(a[rf][kk], bf, acc[rf], 0, 0, 0);
      }
      // exp + accumulate (A pre-scaled, acc is already the exp2 argument)
      #pragma unroll
      for (int rf = 0; rf < 4; rf++)
        #pragma unroll
        for (int r = 0; r < 4; r++)
          s[rf][r] += __builtin_amdgcn_exp2f(acc[rf][r]);
    }
  }

  // reduce across the 16 lanes (cols) of each row-group, then write partials
  #pragma unroll
  for (int rf = 0; rf < 4; rf++)
    #pragma unroll
    for (int r = 0; r < 4; r++) {
      float v = s[rf][r];
      v += __shfl_xor(v, 1, 64);
      v += __shfl_xor(v, 2, 64);
      v += __shfl_xor(v, 4, 64);
      v += __shfl_xor(v, 8, 64);
      s[rf][r] = v;
    }
  if (fr == 0) {
    int rowbase = brow0 + w * 64;
    #pragma unroll
    for (int rf = 0; rf < 4; rf++)
      #pragma unroll
      for (int r = 0; r < 4; r++)
        partials[(size_t)cs * B_ROWS + rowbase + rf * 16 + kq * 4 + r] = s[rf][r];
  }
}

// ---- kernel 3: combine ----
__global__ void finalize(const float* __restrict__ partials, const float* __restrict__ elab,
                         float* __restrict__ out) {
  int b = blockIdx.x * blockDim.x + threadIdx.x;
  if (b >= B_ROWS) return;
  float ssum = 0.f;
  #pragma unroll
  for (int cs = 0; cs < CSPLIT; cs++) ssum += partials[(size_t)cs * B_ROWS + b];
  out[b] = elab[b] / ssum;
}

extern "C" void kernel_launch(void* const* d_in, const int* in_sizes, int n_in,
                              void* d_out, int out_size, void* d_ws, size_t ws_size,
                              hipStream_t stream) {
  const float* x = (const float*)d_in[0];
  const float* cent = (const float*)d_in[1];
  const int* labels = (const int*)d_in[2];
  float* out = (float*)d_out;

  char* ws = (char*)d_ws;
  f16* f16f = (f16*)ws;                                   // 4096*256*2   = 2 MB
  f16* f16c = (f16*)(ws + (size_t)B_ROWS * D_DIM * 2);    // 32768*256*2  = 16 MB
  float* partials = (float*)(ws + (size_t)B_ROWS * D_DIM * 2 + (size_t)C_COLS * D_DIM * 2);
  float* elab = partials + (size_t)CSPLIT * B_ROWS;       // + 1 MB, elab 16 KB

  prep_all<<<CVT_BLOCKS + B_ROWS / 4, 256, 0, stream>>>(x, cent, labels, f16c, f16f, elab);
  gemm_expsum<<<dim3(B_ROWS / BM * CSPLIT), 256, 0, stream>>>(f16f, f16c, partials);
  finalize<<<B_ROWS / 256, 256, 0, stream>>>(partials, elab, out);
}

// Round 5
// 67.311 us; speedup vs baseline: 6.1872x; 6.1872x over previous
//
#include <hip/hip_runtime.h>
#include <stdint.h>

typedef int i32x4 __attribute__((ext_vector_type(4)));
typedef int i32x8 __attribute__((ext_vector_type(8)));
typedef float f32x4 __attribute__((ext_vector_type(4)));

#define B_ROWS 4096
#define C_COLS 32768
#define D_DIM 256
// log2(e) / 0.05
#define LOG2E_OVER_TEMP 28.853900817779268f

#define BM 256                  // rows per block (4 waves x 64 rows)
#define BC 64                   // cols per LDS tile
#define CSPLIT 64
#define CPB (C_COLS / CSPLIT)   // 512 cols per block
#define CTILES (CPB / BC)       // 8 tiles
#define NWAVES 4
#define TILE_BYTES (BC * D_DIM) // 16384 (fp8)
#define CVT_TILES (C_COLS / BC) // 512

typedef __attribute__((address_space(3))) char lds_char_t;
typedef __attribute__((address_space(1))) const char glb_char_t;

// pack 4 f32 -> 4 fp8 e4m3 bytes in one dword (saturating HW cvt)
__device__ __forceinline__ int pack4_fp8(float a, float b, float c, float d) {
  int r = 0;
  r = __builtin_amdgcn_cvt_pk_fp8_f32(a, b, r, false);  // bytes 0,1
  r = __builtin_amdgcn_cvt_pk_fp8_f32(c, d, r, true);   // bytes 2,3
  return r;
}

// ---- kernel 1: prep ----
// blocks [0, 512):  centrals f32 -> fp8 e4m3, permuted into per-tile K-block-major
//                   layout: cq[tile][kb(8)][half(2)][col(64)][16B], 16 KB/tile.
//                   GEMM staging then reads cq linearly (coalesced global_load_lds).
// blocks [512, ...): row-normalize x (pre-scaled by log2e/T) -> fp8 row-major xq,
//                   plus exact fp32 label logit -> elab. One wave per row.
__global__ void prep_all(const float* __restrict__ x, const float* __restrict__ cent,
                         const int* __restrict__ labels, uint8_t* __restrict__ cq,
                         uint8_t* __restrict__ xq, float* __restrict__ elab) {
  int blk = blockIdx.x;
  if (blk < CVT_TILES) {
    int ct = blk;
    #pragma unroll
    for (int i = 0; i < 4; i++) {
      int slot = i * 256 + threadIdx.x;   // 0..1023, 16B each
      int col = slot & 63;
      int half = (slot >> 6) & 1;
      int kb = slot >> 7;                 // 0..7
      int cc = ct * 64 + col;
      const float* src = cent + (size_t)cc * D_DIM + kb * 32 + half * 16;
      float4 v0 = ((const float4*)src)[0];
      float4 v1 = ((const float4*)src)[1];
      float4 v2 = ((const float4*)src)[2];
      float4 v3 = ((const float4*)src)[3];
      int4 o;
      o.x = pack4_fp8(v0.x, v0.y, v0.z, v0.w);
      o.y = pack4_fp8(v1.x, v1.y, v1.z, v1.w);
      o.z = pack4_fp8(v2.x, v2.y, v2.z, v2.w);
      o.w = pack4_fp8(v3.x, v3.y, v3.z, v3.w);
      *(int4*)(cq + (size_t)ct * TILE_BYTES + slot * 16) = o;
    }
  } else {
    int row = (blk - CVT_TILES) * (blockDim.x >> 6) + (threadIdx.x >> 6);
    int lane = threadIdx.x & 63;
    int lab = labels[row];
    const float4 xv = *(const float4*)(x + (size_t)row * D_DIM + lane * 4);
    const float4 cv = *(const float4*)(cent + (size_t)lab * D_DIM + lane * 4);
    float ss = xv.x * xv.x + xv.y * xv.y + xv.z * xv.z + xv.w * xv.w;
    float dc = xv.x * cv.x + xv.y * cv.y + xv.z * cv.z + xv.w * cv.w;
    #pragma unroll
    for (int m = 1; m < 64; m <<= 1) {
      ss += __shfl_xor(ss, m, 64);
      dc += __shfl_xor(dc, m, 64);
    }
    float inv = 1.0f / sqrtf(ss);
    float sc = inv * LOG2E_OVER_TEMP;   // pre-scale: GEMM acc is the exp2 arg
    *(int*)(xq + (size_t)row * D_DIM + lane * 4) =
        pack4_fp8(xv.x * sc, xv.y * sc, xv.z * sc, xv.w * sc);
    if (lane == 0) elab[row] = exp2f(dc * inv * LOG2E_OVER_TEMP);
  }
}

// ---- staging: async global->LDS, 16B/lane, fully linear (cq is pre-permuted) ----
__device__ __forceinline__ void stage_tile(const uint8_t* __restrict__ src, char* buf,
                                           int w, int lane) {
  #pragma unroll
  for (int i = 0; i < 4; i++) {
    int slot_hi = i * NWAVES + w;          // wave-uniform, 0..15
    __builtin_amdgcn_global_load_lds(
        (glb_char_t*)(const void*)(src + slot_hi * 1024 + lane * 16),
        (lds_char_t*)(void*)(buf + slot_hi * 1024), 16, 0, 0);
  }
}

// ---- kernel 2: fused MX-fp8 GEMM + exp + row-sum ----
// 1024 blocks x 256 threads (4 waves). Each wave: 64 rows, A in regs (fp8, 64 VGPR).
// B tile 64 cols x 256 k fp8 = 16 KB, double-buffered, K-block-major:
//   chunk (col, kb, half) at byte kb*2048 + half*1024 + col*16  (16B slot = col&7).
// MFMA: mfma_scale_f32_16x16x128_f8f6f4 with unit scales (e8m0 0x7F = 2^0).
__global__ void __launch_bounds__(256, 3)
gemm_expsum(const uint8_t* __restrict__ xq, const uint8_t* __restrict__ cq,
            float* __restrict__ partials) {
  __shared__ char Bs[2][TILE_BYTES];   // 2 x 16 KB
  const int tid = threadIdx.x;
  const int w = tid >> 6, lane = tid & 63;
  const int fr = lane & 15, kq = lane >> 4;

  // XCD-aware decode: xcd = bid&7 owns cs in [xcd*8, xcd*8+8)
  const int bid = blockIdx.x;
  const int xcd = bid & 7;
  const int j = bid >> 3;                  // 0..127
  const int bx = j & 15;                   // row-block 0..15
  const int cs = xcd * 8 + (j >> 4);       // col-split 0..63
  const int brow0 = bx * BM;
  const int tile0 = cs * CTILES;           // global 64-col tile index

  // A fragments: rows brow0 + w*64 + rf*16 + fr; k = kh*128 + kq*32 .. +32 (32 fp8 = 8 dw)
  i32x8 a[4][2];
  #pragma unroll
  for (int rf = 0; rf < 4; rf++) {
    int row = brow0 + w * 64 + rf * 16 + fr;
    #pragma unroll
    for (int kh = 0; kh < 2; kh++)
      a[rf][kh] = *(const i32x8*)(xq + (size_t)row * D_DIM + kh * 128 + kq * 32);
  }

  float s[4][4] = {{0.f,0.f,0.f,0.f},{0.f,0.f,0.f,0.f},{0.f,0.f,0.f,0.f},{0.f,0.f,0.f,0.f}};
  const f32x4 vzero = {0.f, 0.f, 0.f, 0.f};

  stage_tile(cq + (size_t)tile0 * TILE_BYTES, Bs[0], w, lane);

  for (int t = 0; t < CTILES; t++) {
    __syncthreads();   // implicit vmcnt(0): stage(t) landed; readers of other buf done
    if (t + 1 < CTILES)
      stage_tile(cq + (size_t)(tile0 + t + 1) * TILE_BYTES, Bs[(t + 1) & 1], w, lane);

    const char* buf = Bs[t & 1];
    #pragma unroll
    for (int cf = 0; cf < 4; cf++) {
      const int col = cf * 16 + fr;
      i32x8 bf[2];
      #pragma unroll
      for (int kh = 0; kh < 2; kh++) {
        const int kb = kh * 4 + kq;
        const int off = kb * 2048 + col * 16;
        i32x4 lo = *(const i32x4*)(buf + off);
        i32x4 hi = *(const i32x4*)(buf + off + 1024);
        i32x8 b;
        #pragma unroll
        for (int q = 0; q < 4; q++) { b[q] = lo[q]; b[q + 4] = hi[q]; }
        bf[kh] = b;
      }
      f32x4 acc[4];
      #pragma unroll
      for (int rf = 0; rf < 4; rf++) {
        acc[rf] = __builtin_amdgcn_mfma_scale_f32_16x16x128_f8f6f4(
            a[rf][0], bf[0], vzero, 0, 0, 0, 0x7F7F7F7F, 0, 0x7F7F7F7F);
        acc[rf] = __builtin_amdgcn_mfma_scale_f32_16x16x128_f8f6f4(
            a[rf][1], bf[1], acc[rf], 0, 0, 0, 0x7F7F7F7F, 0, 0x7F7F7F7F);
      }
      // exp + accumulate (A pre-scaled: acc is already the exp2 argument)
      #pragma unroll
      for (int rf = 0; rf < 4; rf++)
        #pragma unroll
        for (int r = 0; r < 4; r++)
          s[rf][r] += __builtin_amdgcn_exp2f(acc[rf][r]);
    }
  }

  // reduce across the 16 col-lanes of each row-group, then write partials
  #pragma unroll
  for (int rf = 0; rf < 4; rf++)
    #pragma unroll
    for (int r = 0; r < 4; r++) {
      float v = s[rf][r];
      v += __shfl_xor(v, 1, 64);
      v += __shfl_xor(v, 2, 64);
      v += __shfl_xor(v, 4, 64);
      v += __shfl_xor(v, 8, 64);
      s[rf][r] = v;
    }
  if (fr == 0) {
    int rowbase = brow0 + w * 64;
    #pragma unroll
    for (int rf = 0; rf < 4; rf++)
      #pragma unroll
      for (int r = 0; r < 4; r++)
        partials[(size_t)cs * B_ROWS + rowbase + rf * 16 + kq * 4 + r] = s[rf][r];
  }
}

// ---- kernel 3: combine ----
__global__ void finalize(const float* __restrict__ partials, const float* __restrict__ elab,
                         float* __restrict__ out) {
  int b = blockIdx.x * blockDim.x + threadIdx.x;
  if (b >= B_ROWS) return;
  float ssum = 0.f;
  #pragma unroll
  for (int cs = 0; cs < CSPLIT; cs++) ssum += partials[(size_t)cs * B_ROWS + b];
  out[b] = elab[b] / ssum;
}

extern "C" void kernel_launch(void* const* d_in, const int* in_sizes, int n_in,
                              void* d_out, int out_size, void* d_ws, size_t ws_size,
                              hipStream_t stream) {
  const float* x = (const float*)d_in[0];
  const float* cent = (const float*)d_in[1];
  const int* labels = (const int*)d_in[2];
  float* out = (float*)d_out;

  char* ws = (char*)d_ws;
  uint8_t* xq = (uint8_t*)ws;                               // 4096*256  = 1 MB
  uint8_t* cq = (uint8_t*)(ws + (size_t)B_ROWS * D_DIM);    // 32768*256 = 8 MB
  float* partials = (float*)(ws + (size_t)B_ROWS * D_DIM + (size_t)C_COLS * D_DIM);
  float* elab = partials + (size_t)CSPLIT * B_ROWS;         // + 1 MB, elab 16 KB

  prep_all<<<CVT_TILES + B_ROWS / 4, 256, 0, stream>>>(x, cent, labels, cq, xq, elab);
  gemm_expsum<<<dim3(B_ROWS / BM * CSPLIT), 256, 0, stream>>>(xq, cq, partials);
  finalize<<<B_ROWS / 256, 256, 0, stream>>>(partials, elab, out);
}